// Round 6
// baseline (142.195 us; speedup 1.0000x reference)
//
#include <hip/hip_runtime.h>

namespace {
constexpr float SCALE = 0.17677669529663687f; // 32^-0.5
constexpr int CHP = 256; // ch-plane stride: 4 row-slots x 64 px, lane-linear

typedef const __attribute__((address_space(1))) void gbl_v;
typedef __attribute__((address_space(3))) void lds_v;
typedef float v2f __attribute__((ext_vector_type(2)));   // -> v_pk_fma_f32

// quad_perm DPP xor-permute (VALU, no LDS pipe): 0xB1 = lane^1, 0x4E = lane^2
template<int CTRL>
__device__ __forceinline__ float qperm(float v) {
  return __builtin_bit_cast(float, __builtin_amdgcn_mov_dpp(
      __builtin_bit_cast(int, v), CTRL, 0xF, 0xF, true));
}

// Block = (image b, head, same-parity row pair {r0, r0+2}). ONE 32 KB LDS
// buffer time-shared: stage K rows {r0-2..r0+4 step 2} x 32 ch (gload_lds w16,
// per-channel f4-slot rotation of the GLOBAL source; LDS dest lane-linear;
// verified 0 bank conflicts) -> QK + reduce + softmax -> barrier -> stage V
// into the SAME buffer -> PV. 32 KB/block => 4 blocks/CU = 32 waves/CU
// (8/SIMD, HW cap) — 2x round-5 occupancy; independent blocks at different
// phases hide each other's barrier drains and staging latency.
// Thread = cg | pp<<3 | rg<<8. cg-reduce: xor1/xor2 via DPP quad_perm (VALU),
// only xor4 via shuffle -> b32 LDS swizzles cut 54 -> 18 per wave.
__global__ __launch_bounds__(512, 8) void dilate_attn(
    const float* __restrict__ q, const float* __restrict__ k,
    const float* __restrict__ v, float* __restrict__ out) {
  __shared__ float sbuf[32 * CHP];   // 32768 B, K then V

  const int tid = threadIdx.x;
  const int cg  = tid & 7;           // 4-channel group
  const int pp  = (tid >> 3) & 31;   // pixel pair (px0 = 2*pp)
  const int rg  = tid >> 8;          // query row within pair (0 -> r0, 1 -> r0+2)

  // XCD swizzle: blk&7 -> XCD; each XCD owns 8 (b,head) combos with row-pairs
  // in order, so halo row re-reads hit that XCD's L2.
  const int blk   = blockIdx.x;
  const int s     = blk >> 3;
  const int combo = ((blk & 7) << 3) | (s >> 5);  // 0..63
  const int pr    = s & 31;                       // row-pair id
  const int r0    = ((pr >> 1) << 2) | (pr & 1);  // base query row (covers 0..63)
  const int b     = combo >> 2;
  const int head  = combo & 3;
  const int qrow  = r0 + 2 * rg;

  const size_t cb = ((size_t)b * 128 + head * 32) * 4096;
  const float* kp = k + cb;
  const float* vp = v + cb;

  // staged row-slot j=0..3 <- source row r0-2+2j (clamped) + validity
  int srow[4]; float vm[4];
  #pragma unroll
  for (int j = 0; j < 4; ++j) {
    const int ry = r0 - 2 + 2 * j;
    const bool ok = (unsigned)ry < 64u;
    srow[j] = (ok ? ry : r0) * 64;
    vm[j]   = ok ? 1.0f : 0.0f;
  }

  // ---- q loads, pre-scaled (independent of staging; overlap with it) ----
  const int px0 = pp << 1;
  v2f q2[4];
  #pragma unroll
  for (int ci = 0; ci < 4; ++ci) {
    q2[ci] = *(const v2f*)(q + cb + (cg * 4 + ci) * 4096 + qrow * 64 + px0);
    q2[ci] *= SCALE;
  }

  // staging addresses: each wave-instruction stages exactly one channel
  // (64 f4 = 4 rows x 16); source f4-slot inverse-rotated by (ch>>2).
  int goff[4], loff[4];
  #pragma unroll
  for (int t = 0; t < 4; ++t) {
    const int l4  = t * 512 + tid;      // f4 slot 0..2047
    const int ch  = l4 >> 6;
    const int rem = l4 & 63;
    const int r   = rem >> 4;
    const int q4  = rem & 15;
    const int pxs = ((q4 - (ch >> 2)) & 15) << 2;
    goff[t] = ch * 4096 + srow[r] + pxs;
    loff[t] = l4 << 2;                  // float offset, lane-linear
  }

  // ---- stage K into sbuf ----
  #pragma unroll
  for (int t = 0; t < 4; ++t)
    __builtin_amdgcn_global_load_lds((gbl_v*)(kp + goff[t]), (lds_v*)(sbuf + loff[t]), 16, 0, 0);
  __syncthreads();   // vmcnt(0): K (and q) retired for all waves

  // column taps (clamped, even) + x masks (same for both px of the pair)
  const int   txL = (pp == 0)  ? 0  : px0 - 2;
  const int   txC = px0;
  const int   txR = (pp == 31) ? 62 : px0 + 2;
  const float mL  = (pp == 0)  ? 0.0f : 1.0f;
  const float mR  = (pp == 31) ? 0.0f : 1.0f;

  // rotated tap offsets: stored float offset of src px p = (p + 4*cg) & 63
  const int rot = cg << 2;
  const int tL  = (txL + rot) & 63;
  const int tC  = (txC + rot) & 63;
  const int tR  = (txR + rot) & 63;

  const int rbase = rg;   // this query row's taps = staged slots rg+0..rg+2

  // ---- Phase 1: partial logits over this thread's 4 channels (pk_fma) ----
  v2f l[9];
  #pragma unroll
  for (int t = 0; t < 9; ++t) l[t] = (v2f)(0.0f);

  #pragma unroll
  for (int r = 0; r < 3; ++r) {
    #pragma unroll
    for (int ci = 0; ci < 4; ++ci) {
      const float* kc = sbuf + (cg * 4 + ci) * CHP + (rbase + r) * 64;
      const v2f kL = *(const v2f*)(kc + tL);
      const v2f kC = *(const v2f*)(kc + tC);
      const v2f kR = *(const v2f*)(kc + tR);
      l[r*3+0] = __builtin_elementwise_fma(q2[ci], kL, l[r*3+0]);
      l[r*3+1] = __builtin_elementwise_fma(q2[ci], kC, l[r*3+1]);
      l[r*3+2] = __builtin_elementwise_fma(q2[ci], kR, l[r*3+2]);
    }
  }

  // combine the 8 cg-partials: xor1 + xor2 via DPP (VALU), xor4 via shuffle
  #pragma unroll
  for (int t = 0; t < 9; ++t) {
    l[t].x += qperm<0xB1>(l[t].x);
    l[t].y += qperm<0xB1>(l[t].y);
  }
  #pragma unroll
  for (int t = 0; t < 9; ++t) {
    l[t].x += qperm<0x4E>(l[t].x);
    l[t].y += qperm<0x4E>(l[t].y);
  }
  #pragma unroll
  for (int t = 0; t < 9; ++t) {
    l[t].x += __shfl_xor(l[t].x, 4, 64);
    l[t].y += __shfl_xor(l[t].y, 4, 64);
  }

  // ---- Phase 2: mask + softmax over 9. No max-subtract: logits are bounded
  // (|l| <~ 7 after scaling) and zero-padded keys contribute exp(0)=1 to the
  // denominator, exactly matching the reference's zero-pad unfold. ----
  float msk[9];
  #pragma unroll
  for (int r = 0; r < 3; ++r) {
    msk[r*3+0] = vm[rbase + r] * mL;
    msk[r*3+1] = vm[rbase + r];
    msk[r*3+2] = vm[rbase + r] * mR;
  }
  v2f sum = (v2f)(0.0f);
  #pragma unroll
  for (int t = 0; t < 9; ++t) {
    l[t] *= msk[t];
    l[t].x = __expf(l[t].x);
    l[t].y = __expf(l[t].y);
    sum += l[t];
  }
  v2f rv; rv.x = 1.0f / sum.x; rv.y = 1.0f / sum.y;
  #pragma unroll
  for (int t = 0; t < 9; ++t)
    l[t] *= rv * msk[t];   // fold V zero-pad into weights

  // ---- all waves done reading K; re-stage V into the same buffer ----
  __syncthreads();
  #pragma unroll
  for (int t = 0; t < 4; ++t)
    __builtin_amdgcn_global_load_lds((gbl_v*)(vp + goff[t]), (lds_v*)(sbuf + loff[t]), 16, 0, 0);
  __syncthreads();   // vmcnt(0): V staged for all waves

  // ---- Phase 3: PV over this thread's 4 channels, from LDS (pk_fma) ----
  v2f o[4];
  #pragma unroll
  for (int ci = 0; ci < 4; ++ci) o[ci] = (v2f)(0.0f);
  #pragma unroll
  for (int r = 0; r < 3; ++r) {
    #pragma unroll
    for (int ci = 0; ci < 4; ++ci) {
      const float* vc = sbuf + (cg * 4 + ci) * CHP + (rbase + r) * 64;
      const v2f vL = *(const v2f*)(vc + tL);
      const v2f vC = *(const v2f*)(vc + tC);
      const v2f vR = *(const v2f*)(vc + tR);
      o[ci] = __builtin_elementwise_fma(l[r*3+0], vL, o[ci]);
      o[ci] = __builtin_elementwise_fma(l[r*3+1], vC, o[ci]);
      o[ci] = __builtin_elementwise_fma(l[r*3+2], vR, o[ci]);
    }
  }

  // ---- Stores: per wave-instr, 8 px x 128B contiguous = full L2 lines ----
  float* ob = out + ((size_t)(b * 64 + qrow) * 64 + px0) * 128 + head * 32 + cg * 4;
  *(float4*)(ob)       = make_float4(o[0].x, o[1].x, o[2].x, o[3].x);
  *(float4*)(ob + 128) = make_float4(o[0].y, o[1].y, o[2].y, o[3].y);
}
} // namespace

extern "C" void kernel_launch(void* const* d_in, const int* in_sizes, int n_in,
                              void* d_out, int out_size, void* d_ws, size_t ws_size,
                              hipStream_t stream) {
  const float* q = (const float*)d_in[0];
  const float* k = (const float*)d_in[1];
  const float* v = (const float*)d_in[2];
  float* o = (float*)d_out;
  // 16 b x 4 heads x 32 same-parity row pairs = 2048 blocks, 512 threads
  dilate_attn<<<dim3(2048), dim3(512), 0, stream>>>(q, k, v, o);
}

// Round 7
// 136.597 us; speedup vs baseline: 1.0410x; 1.0410x over previous
//
#include <hip/hip_runtime.h>

namespace {
constexpr float SCALE = 0.17677669529663687f; // 32^-0.5
constexpr int CHP = 256; // ch-plane stride: 4 row-slots x 64 px, lane-linear

typedef const __attribute__((address_space(1))) void gbl_v;
typedef __attribute__((address_space(3))) void lds_v;
typedef float v2f __attribute__((ext_vector_type(2)));   // -> v_pk_fma_f32

// quad_perm DPP xor-permute (VALU, no LDS pipe): 0xB1 = lane^1, 0x4E = lane^2
template<int CTRL>
__device__ __forceinline__ float qperm(float v) {
  return __builtin_bit_cast(float, __builtin_amdgcn_mov_dpp(
      __builtin_bit_cast(int, v), CTRL, 0xF, 0xF, true));
}

// Block = (image b, head, same-parity row pair {r0, r0+2}). Stage key rows
// {r0-2, r0, r0+2, r0+4} x 32 ch for k and v into SEPARATE LDS buffers via
// global_load_lds (width 16 DMA). Per-channel f4-slot rotation of the GLOBAL
// source (LDS dest lane-linear) -> verified 0 bank conflicts on tap reads.
//
// Pipeline (split-barrier, deep): issue K-stage then V-stage; vmcnt(4) + raw
// s_barrier (K ready, V still in flight); phase-1 K tap-reads + QK fma;
// vmcnt(0) + s_barrier (V ready — no WAR: separate buffers, so this barrier
// moves up BEFORE the reduce); issue all 36 V tap-reads into registers; DPP
// reduce + softmax overlap the V LDS latency; PV is pure register fma.
//
// Thread = cg | pp<<3 | rg<<8. cg-reduce: xor1/xor2 via DPP quad_perm (VALU),
// xor4 via shuffle. Pixel-pair math packed v2f -> v_pk_fma_f32.
__global__ __launch_bounds__(512, 4) void dilate_attn(
    const float* __restrict__ q, const float* __restrict__ k,
    const float* __restrict__ v, float* __restrict__ out) {
  __shared__ float kbuf[32 * CHP];   // 32768 B
  __shared__ float vbuf[32 * CHP];   // 32768 B

  const int tid = threadIdx.x;
  const int cg  = tid & 7;           // 4-channel group
  const int pp  = (tid >> 3) & 31;   // pixel pair (px0 = 2*pp)
  const int rg  = tid >> 8;          // query row within pair (0 -> r0, 1 -> r0+2)

  // XCD swizzle: blk&7 -> XCD; each XCD owns 8 (b,head) combos with row-pairs
  // in order, so halo row re-reads hit that XCD's L2.
  const int blk   = blockIdx.x;
  const int s     = blk >> 3;
  const int combo = ((blk & 7) << 3) | (s >> 5);  // 0..63
  const int pr    = s & 31;                       // row-pair id
  const int r0    = ((pr >> 1) << 2) | (pr & 1);  // base query row (covers 0..63)
  const int b     = combo >> 2;
  const int head  = combo & 3;
  const int qrow  = r0 + 2 * rg;

  const size_t cb = ((size_t)b * 128 + head * 32) * 4096;
  const float* kp = k + cb;
  const float* vp = v + cb;

  // staged row-slot j=0..3 <- source row r0-2+2j (clamped) + validity
  int srow[4]; float vm[4];
  #pragma unroll
  for (int j = 0; j < 4; ++j) {
    const int ry = r0 - 2 + 2 * j;
    const bool ok = (unsigned)ry < 64u;
    srow[j] = (ok ? ry : r0) * 64;
    vm[j]   = ok ? 1.0f : 0.0f;
  }

  // ---- q loads, pre-scaled (independent of staging; overlap with it) ----
  const int px0 = pp << 1;
  v2f q2[4];
  #pragma unroll
  for (int ci = 0; ci < 4; ++ci) {
    q2[ci] = *(const v2f*)(q + cb + (cg * 4 + ci) * 4096 + qrow * 64 + px0);
    q2[ci] *= SCALE;
  }

  // ---- stage K (4 loads) then V (4 loads); vmcnt(4) later retires all K ----
  int goff[4], loff[4];
  #pragma unroll
  for (int t = 0; t < 4; ++t) {
    const int l4  = t * 512 + tid;      // f4 slot 0..2047
    const int ch  = l4 >> 6;            // 64 f4 per channel (4 rows x 16)
    const int rem = l4 & 63;
    const int r   = rem >> 4;           // staged row-slot
    const int q4  = rem & 15;
    const int pxs = ((q4 - (ch >> 2)) & 15) << 2;  // inverse-rotated source px
    goff[t] = ch * 4096 + srow[r] + pxs;
    loff[t] = l4 << 2;                             // float offset, lane-linear
  }
  #pragma unroll
  for (int t = 0; t < 4; ++t)
    __builtin_amdgcn_global_load_lds((gbl_v*)(kp + goff[t]), (lds_v*)(kbuf + loff[t]), 16, 0, 0);
  #pragma unroll
  for (int t = 0; t < 4; ++t)
    __builtin_amdgcn_global_load_lds((gbl_v*)(vp + goff[t]), (lds_v*)(vbuf + loff[t]), 16, 0, 0);

  // wait K only (4 newest outstanding = V); raw barrier avoids vmcnt(0) drain
  asm volatile("s_waitcnt vmcnt(4)" ::: "memory");
  __builtin_amdgcn_s_barrier();
  asm volatile("" ::: "memory");

  // column taps (clamped, even) + x masks (same for both px of the pair)
  const int   txL = (pp == 0)  ? 0  : px0 - 2;
  const int   txC = px0;
  const int   txR = (pp == 31) ? 62 : px0 + 2;
  const float mL  = (pp == 0)  ? 0.0f : 1.0f;
  const float mR  = (pp == 31) ? 0.0f : 1.0f;

  // rotated tap offsets: stored float offset of src px p = (p + 4*cg) & 63
  const int rot = cg << 2;
  const int tL  = (txL + rot) & 63;
  const int tC  = (txC + rot) & 63;
  const int tR  = (txR + rot) & 63;

  const int rbase = rg;   // this query row's taps = staged slots rg+0..rg+2

  // ---- Phase 1: partial logits over this thread's 4 channels (pk_fma) ----
  v2f l[9];
  #pragma unroll
  for (int t = 0; t < 9; ++t) l[t] = (v2f)(0.0f);

  #pragma unroll
  for (int r = 0; r < 3; ++r) {
    #pragma unroll
    for (int ci = 0; ci < 4; ++ci) {
      const float* kc = kbuf + (cg * 4 + ci) * CHP + (rbase + r) * 64;
      const v2f kL = *(const v2f*)(kc + tL);
      const v2f kC = *(const v2f*)(kc + tC);
      const v2f kR = *(const v2f*)(kc + tR);
      l[r*3+0] = __builtin_elementwise_fma(q2[ci], kL, l[r*3+0]);
      l[r*3+1] = __builtin_elementwise_fma(q2[ci], kC, l[r*3+1]);
      l[r*3+2] = __builtin_elementwise_fma(q2[ci], kR, l[r*3+2]);
    }
  }

  // ---- V-ready sync moved up: no WAR on kbuf (separate buffers), so sync as
  // early as possible, then issue V reads so they overlap reduce+softmax ----
  asm volatile("s_waitcnt vmcnt(0)" ::: "memory");
  __builtin_amdgcn_s_barrier();
  asm volatile("" ::: "memory");

  // ---- issue all V tap-reads into registers (consumed only in PV) ----
  v2f vr[3][4][3];
  #pragma unroll
  for (int r = 0; r < 3; ++r) {
    #pragma unroll
    for (int ci = 0; ci < 4; ++ci) {
      const float* vc = vbuf + (cg * 4 + ci) * CHP + (rbase + r) * 64;
      vr[r][ci][0] = *(const v2f*)(vc + tL);
      vr[r][ci][1] = *(const v2f*)(vc + tC);
      vr[r][ci][2] = *(const v2f*)(vc + tR);
    }
  }

  // combine the 8 cg-partials: xor1 + xor2 via DPP (VALU), xor4 via shuffle
  // (overlaps the V LDS reads above)
  #pragma unroll
  for (int t = 0; t < 9; ++t) {
    l[t].x += qperm<0xB1>(l[t].x);
    l[t].y += qperm<0xB1>(l[t].y);
  }
  #pragma unroll
  for (int t = 0; t < 9; ++t) {
    l[t].x += qperm<0x4E>(l[t].x);
    l[t].y += qperm<0x4E>(l[t].y);
  }
  #pragma unroll
  for (int t = 0; t < 9; ++t) {
    l[t].x += __shfl_xor(l[t].x, 4, 64);
    l[t].y += __shfl_xor(l[t].y, 4, 64);
  }

  // ---- Phase 2: mask + softmax over 9. No max-subtract: logits are bounded
  // (|l| <~ 7 after scaling) and zero-padded keys contribute exp(0)=1 to the
  // denominator, exactly matching the reference's zero-pad unfold. ----
  float msk[9];
  #pragma unroll
  for (int r = 0; r < 3; ++r) {
    msk[r*3+0] = vm[rbase + r] * mL;
    msk[r*3+1] = vm[rbase + r];
    msk[r*3+2] = vm[rbase + r] * mR;
  }
  v2f sum = (v2f)(0.0f);
  #pragma unroll
  for (int t = 0; t < 9; ++t) {
    l[t] *= msk[t];
    l[t].x = __expf(l[t].x);
    l[t].y = __expf(l[t].y);
    sum += l[t];
  }
  v2f rv; rv.x = 1.0f / sum.x; rv.y = 1.0f / sum.y;
  #pragma unroll
  for (int t = 0; t < 9; ++t)
    l[t] *= rv * msk[t];   // fold V zero-pad into weights

  // ---- Phase 3: PV — pure register fma (V already in vr) ----
  v2f o[4];
  #pragma unroll
  for (int ci = 0; ci < 4; ++ci) o[ci] = (v2f)(0.0f);
  #pragma unroll
  for (int r = 0; r < 3; ++r) {
    #pragma unroll
    for (int ci = 0; ci < 4; ++ci) {
      o[ci] = __builtin_elementwise_fma(l[r*3+0], vr[r][ci][0], o[ci]);
      o[ci] = __builtin_elementwise_fma(l[r*3+1], vr[r][ci][1], o[ci]);
      o[ci] = __builtin_elementwise_fma(l[r*3+2], vr[r][ci][2], o[ci]);
    }
  }

  // ---- Stores: per wave-instr, 8 px x 128B contiguous = full L2 lines ----
  float* ob = out + ((size_t)(b * 64 + qrow) * 64 + px0) * 128 + head * 32 + cg * 4;
  *(float4*)(ob)       = make_float4(o[0].x, o[1].x, o[2].x, o[3].x);
  *(float4*)(ob + 128) = make_float4(o[0].y, o[1].y, o[2].y, o[3].y);
}
} // namespace

extern "C" void kernel_launch(void* const* d_in, const int* in_sizes, int n_in,
                              void* d_out, int out_size, void* d_ws, size_t ws_size,
                              hipStream_t stream) {
  const float* q = (const float*)d_in[0];
  const float* k = (const float*)d_in[1];
  const float* v = (const float*)d_in[2];
  float* o = (float*)d_out;
  // 16 b x 4 heads x 32 same-parity row pairs = 2048 blocks, 512 threads
  dilate_attn<<<dim3(2048), dim3(512), 0, stream>>>(q, k, v, o);
}